// Round 3
// baseline (897.426 us; speedup 1.0000x reference)
//
#include <hip/hip_runtime.h>
#include <math.h>

#define NCB 4
#define KC 256
#define DIM 64
#define NTOK (64*4096)            // 262144 tokens
#define TPB 512
#define TOKPT 2
#define MGRID (NTOK/(TPB*TOKPT))  // 256 blocks
#define GTPB 256
#define GBLK (NTOK/GTPB)          // 1024 blocks

// ---- workspace byte offsets ----
#define WS_C     0            // 4*256*4   = 4096   (np-exact ||e||^2, f32)
#define WS_P     4096         // 256*64*4  = 65536  (semantic pred table)
#define WS_PVQ   69632        // 256*4
#define WS_PSEM  70656        // 1024*4

// =====================================================================
// Kernel P: np-exact C tables (pairwise-8 sum of e^2) + semantic table
// =====================================================================
__global__ __launch_bounds__(256) void precompute_kernel(
    const float* __restrict__ E,
    const float* __restrict__ W1, const float* __restrict__ b1,
    const float* __restrict__ W2, const float* __restrict__ b2,
    float* __restrict__ Cnp, float* __restrict__ P) {
#pragma clang fp contract(off)
    const int t = threadIdx.x;
    if (blockIdx.x == 0) {
        // np: sq = e*e (separate mul);  pairwise-8 base case for n=64
        for (int i = 0; i < NCB; ++i) {
            const float* row = E + (size_t)(i*KC + t)*DIM;
            float e[DIM];
#pragma unroll
            for (int d = 0; d < DIM; ++d) e[d] = row[d];
            float p[8];
#pragma unroll
            for (int j = 0; j < 8; ++j) p[j] = e[j]*e[j];
#pragma unroll
            for (int m = 1; m < 8; ++m) {
#pragma unroll
                for (int j = 0; j < 8; ++j) {
                    float s = e[m*8+j]*e[m*8+j];
                    p[j] = p[j] + s;
                }
            }
            Cnp[i*KC + t] = ((p[0]+p[1]) + (p[2]+p[3])) + ((p[4]+p[5]) + (p[6]+p[7]));
        }
    } else {
        // P[c] = gelu(E0[c]@W1+b1)@W2+b2  (exact erf gelu; tolerance loose)
        const int c = t;
        float e[DIM];
#pragma unroll
        for (int d = 0; d < DIM; ++d) e[d] = E[(size_t)c*DIM + d];
        float h[DIM];
        for (int m = 0; m < DIM; ++m) {
            float acc = b1[m];
            for (int d = 0; d < DIM; ++d) acc = fmaf(e[d], W1[d*DIM + m], acc);
            h[m] = 0.5f * acc * (1.0f + erff(acc * 0.70710678118654752440f));
        }
        for (int n = 0; n < DIM; ++n) {
            float acc = b2[n];
            for (int m = 0; m < DIM; ++m) acc = fmaf(h[m], W2[m*DIM + n], acc);
            P[c*DIM + n] = acc;
        }
    }
}

// =====================================================================
// Kernel M: bit-exact np-f32 argmin chain, 2 tokens/thread
// =====================================================================
__global__ __launch_bounds__(TPB) void vq_main_kernel(
    const float* __restrict__ z, const float* __restrict__ Eg,
    const float* __restrict__ Cg,
    float* __restrict__ out_codes, float* __restrict__ out_codes0,
    float* __restrict__ partial_vq) {
#pragma clang fp contract(off)
    __shared__ float Elds[KC*DIM];   // 64 KB
    __shared__ float sC[KC];         // 1 KB

    const int tid  = threadIdx.x;
    const int tokA = blockIdx.x * (TPB*TOKPT) + tid;
    const int tokB = tokA + TPB;

    float rA[DIM], rB[DIM];
    {
        const float4* pa = (const float4*)(z + (size_t)tokA * DIM);
        const float4* pb = (const float4*)(z + (size_t)tokB * DIM);
#pragma unroll
        for (int q = 0; q < 16; ++q) {
            float4 a = pa[q], b = pb[q];
            rA[4*q+0]=a.x; rA[4*q+1]=a.y; rA[4*q+2]=a.z; rA[4*q+3]=a.w;
            rB[4*q+0]=b.x; rB[4*q+1]=b.y; rB[4*q+2]=b.z; rB[4*q+3]=b.w;
        }
    }

    int cA[NCB], cB[NCB];
    float vqA = 0.f, vqB = 0.f;

#pragma unroll
    for (int i = 0; i < NCB; ++i) {
        __syncthreads();
        {
            const float4* src = (const float4*)(Eg + (size_t)i*KC*DIM);
            float4* dst = (float4*)Elds;
            for (int x = tid; x < KC*DIM/4; x += TPB) dst[x] = src[x];
            if (tid < KC) sC[tid] = Cg[i*KC + tid];
        }
        __syncthreads();

        // A = np pairwise-8 sum of fl(r*r)  (mul then adds, NO fma)
        float AA, AB;
        {
            float p[8], q8[8];
#pragma unroll
            for (int j = 0; j < 8; ++j) { p[j] = rA[j]*rA[j]; q8[j] = rB[j]*rB[j]; }
#pragma unroll
            for (int m = 1; m < 8; ++m) {
#pragma unroll
                for (int j = 0; j < 8; ++j) {
                    float sa = rA[m*8+j]*rA[m*8+j]; p[j]  = p[j]  + sa;
                    float sb = rB[m*8+j]*rB[m*8+j]; q8[j] = q8[j] + sb;
                }
            }
            AA = ((p[0]+p[1]) + (p[2]+p[3])) + ((p[4]+p[5]) + (p[6]+p[7]));
            AB = ((q8[0]+q8[1]) + (q8[2]+q8[3])) + ((q8[4]+q8[5]) + (q8[6]+q8[7]));
        }

        // scan: d2_k = fl(fl(A - 2*dot_k) + C_k), dot = sequential fma chain
        float bestA = INFINITY, bestB = INFINITY;
        int iA = 0, iB = 0;
        for (int k = 0; k < KC; ++k) {
            const float* e = Elds + k*DIM;
            float dA = 0.f, dB = 0.f;
#pragma unroll
            for (int d4 = 0; d4 < 16; ++d4) {
                float4 ev = *(const float4*)(e + 4*d4);
                dA = fmaf(rA[4*d4+0], ev.x, dA); dA = fmaf(rA[4*d4+1], ev.y, dA);
                dA = fmaf(rA[4*d4+2], ev.z, dA); dA = fmaf(rA[4*d4+3], ev.w, dA);
                dB = fmaf(rB[4*d4+0], ev.x, dB); dB = fmaf(rB[4*d4+1], ev.y, dB);
                dB = fmaf(rB[4*d4+2], ev.z, dB); dB = fmaf(rB[4*d4+3], ev.w, dB);
            }
            // B_k = 2*dot exact (power-of-2); fl(A - B_k) == fmaf(-2,dot,A)
            const float d1A = fmaf(-2.0f, dA, AA);
            const float d2A = d1A + sC[k];
            const float d1B = fmaf(-2.0f, dB, AB);
            const float d2B = d1B + sC[k];
            if (d2A < bestA) { bestA = d2A; iA = k; }   // first-min, like np.argmin
            if (d2B < bestB) { bestB = d2B; iB = k; }
        }
        cA[i] = iA; cB[i] = iB;

        // residual update, np-exact straight-through chain:
        // t = fl(e - r); st = fl(r + t); r = fl(r - st)
        const float* eA = Elds + iA*DIM;
        const float* eB = Elds + iB*DIM;
#pragma unroll
        for (int d4 = 0; d4 < 16; ++d4) {
            float4 ea = *(const float4*)(eA + 4*d4);
            float4 eb = *(const float4*)(eB + 4*d4);
            {
                float t, st;
                t = ea.x - rA[4*d4+0]; vqA = fmaf(t,t,vqA); st = rA[4*d4+0] + t; rA[4*d4+0] = rA[4*d4+0] - st;
                t = ea.y - rA[4*d4+1]; vqA = fmaf(t,t,vqA); st = rA[4*d4+1] + t; rA[4*d4+1] = rA[4*d4+1] - st;
                t = ea.z - rA[4*d4+2]; vqA = fmaf(t,t,vqA); st = rA[4*d4+2] + t; rA[4*d4+2] = rA[4*d4+2] - st;
                t = ea.w - rA[4*d4+3]; vqA = fmaf(t,t,vqA); st = rA[4*d4+3] + t; rA[4*d4+3] = rA[4*d4+3] - st;
                t = eb.x - rB[4*d4+0]; vqB = fmaf(t,t,vqB); st = rB[4*d4+0] + t; rB[4*d4+0] = rB[4*d4+0] - st;
                t = eb.y - rB[4*d4+1]; vqB = fmaf(t,t,vqB); st = rB[4*d4+1] + t; rB[4*d4+1] = rB[4*d4+1] - st;
                t = eb.z - rB[4*d4+2]; vqB = fmaf(t,t,vqB); st = rB[4*d4+2] + t; rB[4*d4+2] = rB[4*d4+2] - st;
                t = eb.w - rB[4*d4+3]; vqB = fmaf(t,t,vqB); st = rB[4*d4+3] + t; rB[4*d4+3] = rB[4*d4+3] - st;
            }
        }
    }

    *(float4*)(out_codes + (size_t)tokA*4) =
        make_float4((float)cA[0], (float)cA[1], (float)cA[2], (float)cA[3]);
    *(float4*)(out_codes + (size_t)tokB*4) =
        make_float4((float)cB[0], (float)cB[1], (float)cB[2], (float)cB[3]);
    out_codes0[tokA] = (float)cA[0];
    out_codes0[tokB] = (float)cB[0];

    // deterministic block reduction of vq partial (reuse LDS)
    __syncthreads();
    float* red = (float*)Elds;
    red[tid] = vqA + vqB;
    __syncthreads();
    for (int off = TPB/2; off > 0; off >>= 1) {
        if (tid < off) red[tid] += red[tid + off];
        __syncthreads();
    }
    if (tid == 0) partial_vq[blockIdx.x] = red[0];
}

// =====================================================================
// Kernel G: z_q_total via np-exact straight-through chain + semantic
// =====================================================================
__global__ __launch_bounds__(GTPB) void gather_kernel(
    const float* __restrict__ codesf, const float* __restrict__ z,
    const float* __restrict__ Eg, const float* __restrict__ P,
    const float* __restrict__ w2v,
    float* __restrict__ zq, float* __restrict__ partial_sem) {
#pragma clang fp contract(off)
    __shared__ float red[GTPB];
    const int tid = threadIdx.x;
    const int tok = blockIdx.x * GTPB + tid;

    float4 cf = *(const float4*)(codesf + (size_t)tok*4);
    const int c0 = (int)cf.x, c1 = (int)cf.y, c2 = (int)cf.z, c3 = (int)cf.w;

    const float4* zp = (const float4*)(z + (size_t)tok*DIM);
    const float4* e0 = (const float4*)(Eg + (size_t)(0*KC + c0)*DIM);
    const float4* e1 = (const float4*)(Eg + (size_t)(1*KC + c1)*DIM);
    const float4* e2 = (const float4*)(Eg + (size_t)(2*KC + c2)*DIM);
    const float4* e3 = (const float4*)(Eg + (size_t)(3*KC + c3)*DIM);
    float4* o = (float4*)(zq + (size_t)tok*DIM);

    const float4* pp = (const float4*)(P + (size_t)c0*DIM);
    const float4* wv = (const float4*)(w2v + (size_t)tok*DIM);
    float sem = 0.f;

#pragma unroll
    for (int q = 0; q < 16; ++q) {
        float4 zv = zp[q], a = e0[q], b = e1[q], c = e2[q], d = e3[q];
        float4 out;
        // per component: replicate the reference's f32 chain
        {
            float r, t, st, tot;
            r = zv.x;
            t = a.x - r; st = r + t; tot = st;        r = r - st;
            t = b.x - r; st = r + t; tot = tot + st;  r = r - st;
            t = c.x - r; st = r + t; tot = tot + st;  r = r - st;
            t = d.x - r; st = r + t; tot = tot + st;
            out.x = tot;
        }
        {
            float r, t, st, tot;
            r = zv.y;
            t = a.y - r; st = r + t; tot = st;        r = r - st;
            t = b.y - r; st = r + t; tot = tot + st;  r = r - st;
            t = c.y - r; st = r + t; tot = tot + st;  r = r - st;
            t = d.y - r; st = r + t; tot = tot + st;
            out.y = tot;
        }
        {
            float r, t, st, tot;
            r = zv.z;
            t = a.z - r; st = r + t; tot = st;        r = r - st;
            t = b.z - r; st = r + t; tot = tot + st;  r = r - st;
            t = c.z - r; st = r + t; tot = tot + st;  r = r - st;
            t = d.z - r; st = r + t; tot = tot + st;
            out.z = tot;
        }
        {
            float r, t, st, tot;
            r = zv.w;
            t = a.w - r; st = r + t; tot = st;        r = r - st;
            t = b.w - r; st = r + t; tot = tot + st;  r = r - st;
            t = c.w - r; st = r + t; tot = tot + st;  r = r - st;
            t = d.w - r; st = r + t; tot = tot + st;
            out.w = tot;
        }
        o[q] = out;

        float4 pv = pp[q], wvv = wv[q];
        float df;
        df = pv.x - wvv.x; sem = fmaf(df, df, sem);
        df = pv.y - wvv.y; sem = fmaf(df, df, sem);
        df = pv.z - wvv.z; sem = fmaf(df, df, sem);
        df = pv.w - wvv.w; sem = fmaf(df, df, sem);
    }

    red[tid] = sem;
    __syncthreads();
    for (int off = GTPB/2; off > 0; off >>= 1) {
        if (tid < off) red[tid] += red[tid + off];
        __syncthreads();
    }
    if (tid == 0) partial_sem[blockIdx.x] = red[0];
}

// =====================================================================
// Kernel R: deterministic final reduction -> loss scalars
// =====================================================================
__global__ __launch_bounds__(256) void reduce_kernel(
    const float* __restrict__ pvq, const float* __restrict__ psem,
    float* __restrict__ out_loss) {
    __shared__ float sv[256], ss[256];
    const int t = threadIdx.x;
    float a = pvq[t];                       // MGRID == 256
    float b = 0.f;
    for (int x = t; x < GBLK; x += 256) b += psem[x];
    sv[t] = a; ss[t] = b;
    __syncthreads();
    for (int off = 128; off > 0; off >>= 1) {
        if (t < off) { sv[t] += sv[t+off]; ss[t] += ss[t+off]; }
        __syncthreads();
    }
    if (t == 0) {
        // vq_loss = sum_i (1+0.25)*mean(t^2); semantic = mean((pred-w2v)^2)
        out_loss[0] = 1.25f * sv[0] / 16777216.0f;
        out_loss[1] = ss[0] / 16777216.0f;
    }
}

extern "C" void kernel_launch(void* const* d_in, const int* in_sizes, int n_in,
                              void* d_out, int out_size, void* d_ws, size_t ws_size,
                              hipStream_t stream) {
    (void)in_sizes; (void)n_in; (void)out_size; (void)ws_size;
    const float* z   = (const float*)d_in[0];
    const float* w2v = (const float*)d_in[1];
    const float* E   = (const float*)d_in[2];
    const float* W1  = (const float*)d_in[3];
    const float* b1  = (const float*)d_in[4];
    const float* W2  = (const float*)d_in[5];
    const float* b2  = (const float*)d_in[6];

    float* out = (float*)d_out;
    char*  ws  = (char*)d_ws;
    float* Cnp  = (float*)(ws + WS_C);
    float* P    = (float*)(ws + WS_P);
    float* pvq  = (float*)(ws + WS_PVQ);
    float* psem = (float*)(ws + WS_PSEM);

    float* out_zq     = out;                        // [B,T,64]
    float* out_codes  = out + 16777216;             // [B,T,4]
    float* out_codes0 = out + 17825792;             // [B,T]
    float* out_loss   = out + 18087936;             // vq_loss, semantic_loss

    precompute_kernel<<<2, 256, 0, stream>>>(E, W1, b1, W2, b2, Cnp, P);
    vq_main_kernel<<<MGRID, TPB, 0, stream>>>(z, E, Cnp, out_codes, out_codes0, pvq);
    gather_kernel<<<GBLK, GTPB, 0, stream>>>(out_codes, z, E, P, w2v, out_zq, psem);
    reduce_kernel<<<1, 256, 0, stream>>>(pvq, psem, out_loss);
}